// Round 1
// baseline (435.298 us; speedup 1.0000x reference)
//
#include <hip/hip_runtime.h>
#include <math.h>

#define C 64
#define D 16
#define EPSF 1e-8f
#define DVAR 0.5f
#define DDIST 1.5f
#define FPSCALE 65536.0f
#define INV_FPSCALE (1.0f / 65536.0f)
#define VARSCALE 4294967296.0
#define INV_VARSCALE (1.0 / 4294967296.0)

// ws layout (32-bit words): [0,1024) g_sums (int, x2^16 fixed-point),
// [1024,1088) g_cnt (uint), [1088,1090) g_var (u64, x2^32 fixed-point; byte 4352, 8-aligned)
__global__ __launch_bounds__(256) void k_zero(int* ws, int n) {
    int i = blockIdx.x * 256 + threadIdx.x;
    if (i < n) ws[i] = 0;
}

// Quarter-point scheme: thread t handles quarter q=t&3 of point pr=t>>2 of a
// 64-point tile. Global loads are f4[tile*256+t] -> contiguous 1KB per wave
// instruction (vs 64 scattered 64B segments in the 4-float4-per-thread form).
__global__ __launch_bounds__(256) void k_sums(const float4* __restrict__ f4,
                                              const int* __restrict__ labels, int N,
                                              int* __restrict__ g_sums,
                                              unsigned* __restrict__ g_cnt) {
    // int fixed-point LDS histogram (native ds_add).
    // REVERSE tile order: ends on the array head so k_hinge (forward) hits L3.
    __shared__ int s_sums[C * 17];
    __shared__ unsigned s_cnt[C];
    int t = threadIdx.x;
    for (int i = t; i < C * 17; i += 256) s_sums[i] = 0;
    if (t < C) s_cnt[t] = 0u;
    __syncthreads();

    int q = t & 3;        // quarter (which 4 components)
    int pr = t >> 2;      // point within tile (0..63)
    int ntiles = (N + 63) >> 6;   // 64 points per tile per block
    for (int it = blockIdx.x; it < ntiles; it += gridDim.x) {
        int tile = ntiles - 1 - it;
        int p = (tile << 6) + pr;
        if (p >= N) continue;
        int c = labels[p] & (C - 1);
        float4 v = f4[(tile << 8) + t];   // == f4[4*p+q], fully coalesced
        // address = c*17 + 4q + k: same-address collision needs same (c,q)
        // -> only 16 candidate lanes per instruction (was 64).
        int* row = &s_sums[c * 17 + (q << 2)];
        atomicAdd(row + 0, __float2int_rn(v.x * FPSCALE));
        atomicAdd(row + 1, __float2int_rn(v.y * FPSCALE));
        atomicAdd(row + 2, __float2int_rn(v.z * FPSCALE));
        atomicAdd(row + 3, __float2int_rn(v.w * FPSCALE));
        if (q == 0) atomicAdd(&s_cnt[c], 1u);
    }
    __syncthreads();
    // flush with NATIVE int global atomics (fp atomicAdd w/o -munsafe-fp-atomics = CAS loop)
    for (int i = t; i < C * D; i += 256) {
        int c = i >> 4, d = i & 15;
        atomicAdd(&g_sums[i], s_sums[c * 17 + d]);
    }
    if (t < C) atomicAdd(&g_cnt[t], s_cnt[t]);
}

__global__ __launch_bounds__(256) void k_hinge(const float4* __restrict__ f4,
                                               const int* __restrict__ labels, int N,
                                               const int* __restrict__ g_sums,
                                               const unsigned* __restrict__ g_cnt,
                                               unsigned long long* __restrict__ g_var) {
    // forward order to consume the L3-resident head left by k_sums.
    __shared__ __align__(16) float s_means[C * 20];
    __shared__ float s_w[C];
    __shared__ float s_red[256];
    int t = threadIdx.x;
    for (int i = t; i < C * D; i += 256) {
        int c = i >> 4, d = i & 15;
        s_means[c * 20 + d] = (float)g_sums[i] * INV_FPSCALE / fmaxf((float)g_cnt[c], 1.0f);
    }
    // 0.25 folds out the 4x duplicate accumulation (all 4 quarter-lanes add the
    // full h^2 after the butterfly), so partials keep the old meaning/scale.
    if (t < C) s_w[t] = 0.25f / (fmaxf((float)g_cnt[t], 1.0f) * (float)C);
    __syncthreads();

    int q = t & 3;
    int pr = t >> 2;
    float acc = 0.0f;
    int ntiles = (N + 63) >> 6;
    for (int tile = blockIdx.x; tile < ntiles; tile += gridDim.x) {
        int p = (tile << 6) + pr;
        if (p >= N) continue;   // all 4 lanes of a quad share p -> shuffle-safe
        int c = labels[p] & (C - 1);
        float4 v = f4[(tile << 8) + t];                         // coalesced 1KB/wave
        float4 m = *(const float4*)&s_means[c * 20 + (q << 2)]; // 16B-aligned
        float dx, ss;
        dx = v.x - m.x + EPSF; ss  = dx * dx;
        dx = v.y - m.y + EPSF; ss += dx * dx;
        dx = v.z - m.z + EPSF; ss += dx * dx;
        dx = v.w - m.w + EPSF; ss += dx * dx;
        // complete ||f-m||^2 within the 4-lane quad
        ss += __shfl_xor(ss, 1);
        ss += __shfl_xor(ss, 2);
        float h = fmaxf(sqrtf(ss) - DVAR, 0.0f);
        acc += h * h * s_w[c];
    }
    s_red[t] = acc;
    __syncthreads();
    for (int s = 128; s > 0; s >>= 1) {
        if (t < s) s_red[t] += s_red[t + s];
        __syncthreads();
    }
    // one NATIVE u64 atomic per block (partials are non-negative)
    if (t == 0) {
        unsigned long long qv = (unsigned long long)((double)s_red[0] * VARSCALE + 0.5);
        atomicAdd(g_var, qv);
    }
}

__global__ __launch_bounds__(256) void k_final(const int* __restrict__ g_sums,
                                               const unsigned* __restrict__ g_cnt,
                                               const unsigned long long* __restrict__ g_var,
                                               float* __restrict__ out) {
    __shared__ float s_m[C * 17];
    __shared__ float red[256];
    int t = threadIdx.x;
    for (int i = t; i < C * D; i += 256) {
        int c = i >> 4, d = i & 15;
        s_m[c * 17 + d] = (float)g_sums[i] * INV_FPSCALE / fmaxf((float)g_cnt[c], 1.0f);
    }
    __syncthreads();

    float var_loss = (float)((double)g_var[0] * INV_VARSCALE);

    // dist_loss over ordered pairs i != j
    float ds = 0.0f;
    for (int p = t; p < C * C; p += 256) {
        int i = p >> 6, j = p & 63;
        if (i != j) {
            float ss = 0.0f;
            #pragma unroll
            for (int d = 0; d < D; d++) {
                float df = s_m[i * 17 + d] - s_m[j * 17 + d] + EPSF;
                ss += df * df;
            }
            float h = fmaxf(2.0f * DDIST - sqrtf(ss), 0.0f);
            ds += h * h;
        }
    }
    red[t] = ds;
    __syncthreads();
    for (int s = 128; s > 0; s >>= 1) {
        if (t < s) red[t] += red[t + s];
        __syncthreads();
    }
    float dist_loss = red[0] / (float)(C * (C - 1));
    __syncthreads();

    // reg_loss = mean_c ||m_c + EPS||
    float rg = 0.0f;
    if (t < C) {
        float ss = 0.0f;
        #pragma unroll
        for (int d = 0; d < D; d++) {
            float m = s_m[t * 17 + d] + EPSF;
            ss += m * m;
        }
        rg = sqrtf(ss);
    }
    red[t] = rg;
    __syncthreads();
    for (int s = 128; s > 0; s >>= 1) {
        if (t < s) red[t] += red[t + s];
        __syncthreads();
    }
    float reg_loss = red[0] / (float)C;

    if (t == 0) {
        out[0] = var_loss + dist_loss + 0.001f * reg_loss;
        out[1] = var_loss;
        out[2] = dist_loss;
        out[3] = reg_loss;
    }
}

extern "C" void kernel_launch(void* const* d_in, const int* in_sizes, int n_in,
                              void* d_out, int out_size, void* d_ws, size_t ws_size,
                              hipStream_t stream) {
    const float* features = (const float*)d_in[0];
    const int* labels = (const int*)d_in[1];
    int N = in_sizes[0] / D;

    int* ws = (int*)d_ws;
    int* g_sums = ws;                                             // 1024 ints (x2^16)
    unsigned* g_cnt = (unsigned*)(ws + 1024);                     // 64 uints
    unsigned long long* g_var = (unsigned long long*)(ws + 1088); // u64 (x2^32), 8-aligned
    float* out = (float*)d_out;

    hipLaunchKernelGGL(k_zero, dim3(5), dim3(256), 0, stream, ws, 1090);
    hipLaunchKernelGGL(k_sums, dim3(2048), dim3(256), 0, stream,
                       (const float4*)features, labels, N, g_sums, g_cnt);
    hipLaunchKernelGGL(k_hinge, dim3(2048), dim3(256), 0, stream,
                       (const float4*)features, labels, N, g_sums, g_cnt, g_var);
    hipLaunchKernelGGL(k_final, dim3(1), dim3(256), 0, stream, g_sums, g_cnt, g_var, out);
}